// Round 9
// baseline (338.587 us; speedup 1.0000x reference)
//
#include <hip/hip_runtime.h>

// Problem constants (fixed by setup_inputs)
static constexpr int Bb = 2, Nn = 128, Ll = 128, Hh = 8, Ee = 64;
static constexpr float SCALE = 0.125f;  // 1/sqrt(E)

typedef short short8 __attribute__((ext_vector_type(8)));   // 8 bf16 in 4 VGPRs
typedef float float4v __attribute__((ext_vector_type(4)));  // MFMA C/D

#define MFMA16(a, b, c) __builtin_amdgcn_mfma_f32_16x16x32_bf16(a, b, c, 0, 0, 0)

__device__ inline unsigned short bf16_rne(float f) {
  unsigned u = __builtin_bit_cast(unsigned, f);
  u += 0x7FFFu + ((u >> 16) & 1u);
  return (unsigned short)(u >> 16);
}

// hi = bf16 truncation, lo = bf16 RNE of residual.  hi*hi + hi*lo + lo*hi
// reconstructs the product to ~2^-15.5 rel.  (Identical numerics to R0-R8.)
__device__ inline void split8(float4 a, float4 b, short8& hi, short8& lo) {
  float f[8] = {a.x, a.y, a.z, a.w, b.x, b.y, b.z, b.w};
#pragma unroll
  for (int j = 0; j < 8; ++j) {
    unsigned u = __builtin_bit_cast(unsigned, f[j]);
    unsigned short h = (unsigned short)(u >> 16);
    hi[j] = (short)h;
    float hf = __builtin_bit_cast(float, (unsigned)h << 16);
    lo[j] = (short)bf16_rne(f[j] - hf);
  }
}

__device__ inline short8 pack4(const unsigned* p) {
  union { unsigned u[4]; short8 s; } t;
  t.u[0] = p[0]; t.u[1] = p[1]; t.u[2] = p[2]; t.u[3] = p[3];
  return t.s;  // u32 = 2 consecutive bf16 (low halfword = even k) = frag pair
}

// Within-wave LDS fence: this wave's ds_writes complete before its ds_reads.
// NOT a block barrier.  "memory" clobber orders the (memory-op) LDS accesses
// at compile time; sched_barrier pins it (guide rule #18).
__device__ inline void wave_lds_fence() {
  __builtin_amdgcn_sched_barrier(0);
  asm volatile("s_waitcnt lgkmcnt(0)" ::: "memory");
  __builtin_amdgcn_sched_barrier(0);
}

// Round-9 restructure: ONE block barrier, then fully independent waves.
//   - V staged cooperatively to LDS (the only shared data needing a barrier).
//   - Each wave owns 16 output rows end-to-end: Q load+split, QK GEMM with
//     K read DIRECTLY from global (16 lanes share lines -> L1-hot after the
//     first wave; no K-LDS, no K barriers), softmax with inline mask loads,
//     P transpose through a PRIVATE per-wave LDS slice (within-wave lgkmcnt
//     fence only -- P never crosses waves), PV GEMM, store.
//   - 24 resident waves/CU free-run at different phases -> TLP hides every
//     latency that the R2-R8 lockstep structure exposed.
//
// SPATIAL=false (temporal): idx=n, rows=l, V fp32 [B,N,L,H,E], out=Vt bf16
//                           layout [B,L,H,M,E]
// SPATIAL=true  (spatial) : idx=l, rows=n, V=Vt bf16 (contiguous slice),
//                           multiplicative mask, out fp32
template <bool SPATIAL>
__global__ __launch_bounds__(512, 4) void st_attn(
    const float* __restrict__ Qp, const float* __restrict__ Kp,
    const void* __restrict__ Vp, const float* __restrict__ Mp,
    void* __restrict__ Op, int idx_stride, int row_stride) {
  // Per-wave P slices: wave w owns Pb[w*2080 .. +2080) (16 rows x 130 u16,
  // odd stride for bank spread).  33,280 B.
  __shared__ __align__(16) unsigned short Pb[8 * 16 * 130];
  // V^T bf16: Vb[d][c], stride 130.  16,640 B.  Total 49,920 B -> up to
  // 3 blocks/CU by LDS (VGPR permitting).
  __shared__ __align__(16) unsigned short Vb[64 * 130];

  const int g = blockIdx.x;
  const int b = g >> 10;
  const int idx = (g >> 3) & 127;
  const int h = g & 7;
  const int base = b * (Nn * Ll * Hh * Ee) + idx * idx_stride + h * Ee;

  const int tid = threadIdx.x;
  const int wave = tid >> 6;   // 0..7
  const int lane = tid & 63;
  const int tx = lane & 15;    // MFMA m/n lane index
  const int quad = lane >> 4;  // MFMA k-chunk / row-quad
  const int rowbase = wave * 16;        // this wave's 16 output rows
  const int rowb = rowbase + quad * 4;  // C/D row = quad*4+e
  const int mb = b * (Nn * Nn);

  // ======== stage V -> LDS (cooperative), the ONLY block-wide sync ========
  if constexpr (SPATIAL) {
    // V_t slice [b, idx=l, h, :, :] = 8192 bf16, contiguous.
    const unsigned short* vsl =
        (const unsigned short*)Vp + ((b * Ll + idx) * Hh + h) * (Nn * Ee);
#pragma unroll
    for (int it = 0; it < 2; ++it) {
      const int i8 = tid + it * 512;  // 0..1023 chunks of 8 bf16
      union { float4 f; unsigned short u[8]; } t;
      t.f = *(const float4*)(vsl + i8 * 8);
      const int m = i8 >> 3;        // node m 0..127
      const int e0 = (i8 & 7) * 8;  // dim 0..56
#pragma unroll
      for (int j = 0; j < 8; ++j) Vb[(e0 + j) * 130 + m] = t.u[j];
    }
  } else {
    const float* Vf = (const float*)Vp;
#pragma unroll
    for (int it = 0; it < 4; ++it) {
      const int i4 = tid + it * 512;
      const int c = i4 >> 4;             // V row 0..127
      const int d0 = (i4 & 15) << 2;     // V col 0..60
      const float4 v = *(const float4*)(Vf + base + c * row_stride + d0);
      Vb[(d0 + 0) * 130 + c] = bf16_rne(v.x);
      Vb[(d0 + 1) * 130 + c] = bf16_rne(v.y);
      Vb[(d0 + 2) * 130 + c] = bf16_rne(v.z);
      Vb[(d0 + 3) * 130 + c] = bf16_rne(v.w);
    }
  }

  __syncthreads();  // V staged; waves are independent from here on

  // ======== Q: own rows, hi/lo split fragments =============================
  short8 qhi[2], qlo[2];
  {
    const float* qr = Qp + base + (rowbase + tx) * row_stride;
#pragma unroll
    for (int ks = 0; ks < 2; ++ks) {
      const float4 a = *(const float4*)(qr + ks * 32 + quad * 8);
      const float4 c = *(const float4*)(qr + ks * 32 + quad * 8 + 4);
      split8(a, c, qhi[ks], qlo[ks]);
    }
  }

  // ======== score GEMM: S = Q*K^T, K direct from global (L1-shared) =======
  float4v acc[8];
#pragma unroll
  for (int ct = 0; ct < 8; ++ct) acc[ct] = (float4v)(0.0f);

#pragma unroll
  for (int ct = 0; ct < 8; ++ct) {
    const float* kr = Kp + base + (ct * 16 + tx) * row_stride;
#pragma unroll
    for (int ks = 0; ks < 2; ++ks) {
      const float4 a = *(const float4*)(kr + ks * 32 + quad * 8);
      const float4 c = *(const float4*)(kr + ks * 32 + quad * 8 + 4);
      short8 khi, klo;
      split8(a, c, khi, klo);
      acc[ct] = MFMA16(qhi[ks], khi, acc[ct]);
      acc[ct] = MFMA16(qhi[ks], klo, acc[ct]);
      acc[ct] = MFMA16(qlo[ks], khi, acc[ct]);
    }
  }

  // ======== softmax: scale/(mask)/exp, exact fp32 rowsums ==================
  float rowsum[4] = {0.f, 0.f, 0.f, 0.f};
#pragma unroll
  for (int ct = 0; ct < 8; ++ct) {
    float mv[4];
    if constexpr (SPATIAL) {
#pragma unroll
      for (int e = 0; e < 4; ++e)
        mv[e] = Mp[mb + (rowb + e) * 128 + ct * 16 + tx];
    }
#pragma unroll
    for (int e = 0; e < 4; ++e) {
      float p = acc[ct][e] * SCALE;
      if (SPATIAL) p *= mv[e];
      p = __expf(p);
      rowsum[e] += p;   // exact fp32 denominator (pre-rounding)
      acc[ct][e] = p;
    }
  }

  float inv[4];
#pragma unroll
  for (int e = 0; e < 4; ++e) {
    float s = rowsum[e];
#pragma unroll
    for (int d = 1; d < 16; d <<= 1) s += __shfl_xor(s, d);
    inv[e] = 1.0f / s;
  }

  // ======== P transpose via PRIVATE LDS slice (no block barrier) ===========
  unsigned short* myP = Pb + wave * (16 * 130);
#pragma unroll
  for (int ct = 0; ct < 8; ++ct) {
    const int col = ct * 16 + tx;
#pragma unroll
    for (int e = 0; e < 4; ++e)
      myP[(quad * 4 + e) * 130 + col] = bf16_rne(acc[ct][e]);
  }

  wave_lds_fence();  // own writes visible to own reads; other waves untouched

  // ======== PV GEMM: A = own P rows, B = V^T rows (shared, post-barrier) ==
  float4v accO[4];
#pragma unroll
  for (int dt = 0; dt < 4; ++dt) accO[dt] = (float4v)(0.0f);

#pragma unroll
  for (int ks = 0; ks < 4; ++ks) {
    const short8 pA =
        pack4((const unsigned*)myP + tx * 65 + ks * 16 + quad * 4);
#pragma unroll
    for (int dt = 0; dt < 4; ++dt) {
      const short8 vB =
          pack4((const unsigned*)Vb + (dt * 16 + tx) * 65 + ks * 16 + quad * 4);
      accO[dt] = MFMA16(pA, vB, accO[dt]);
    }
  }

  // ======== normalize + store =============================================
  if constexpr (SPATIAL) {
    float* O = (float*)Op;
#pragma unroll
    for (int dt = 0; dt < 4; ++dt)
#pragma unroll
      for (int e = 0; e < 4; ++e)
        O[base + (rowb + e) * row_stride + dt * 16 + tx] =
            accO[dt][e] * inv[e];
  } else {
    // V_t out: bf16, layout [B, L, H, M, E]; row = l, idx = n.
    unsigned short* O = (unsigned short*)Op;
#pragma unroll
    for (int dt = 0; dt < 4; ++dt)
#pragma unroll
      for (int e = 0; e < 4; ++e)
        O[((b * Ll + (rowb + e)) * Hh + h) * (Nn * Ee) + idx * Ee + dt * 16 +
          tx] = bf16_rne(accO[dt][e] * inv[e]);
  }
}

extern "C" void kernel_launch(void* const* d_in, const int* in_sizes, int n_in,
                              void* d_out, int out_size, void* d_ws,
                              size_t ws_size, hipStream_t stream) {
  const float* Q = (const float*)d_in[0];
  const float* K = (const float*)d_in[1];
  const float* V = (const float*)d_in[2];
  const float* M = (const float*)d_in[3];
  float* out = (float*)d_out;
  unsigned short* Vt = (unsigned short*)d_ws;  // 33.5 MiB bf16 [B,L,H,M,E]

  dim3 grid(Bb * Nn * Hh), blk(512);  // 2048 blocks x 8 waves
  // Temporal: per (b,n,h), rows = l
  st_attn<false><<<grid, blk, 0, stream>>>(Q, K, (const void*)V, nullptr,
                                           (void*)Vt, Ll * Hh * Ee /*n*/,
                                           Hh * Ee /*l*/);
  // Spatial: per (b,l,h), rows = n, V operand = V_t bf16
  st_attn<true><<<grid, blk, 0, stream>>>(Q, K, (const void*)Vt, M,
                                          (void*)out, Hh * Ee /*l*/,
                                          Ll * Hh * Ee /*n*/);
}

// Round 10
// 262.373 us; speedup vs baseline: 1.2905x; 1.2905x over previous
//
#include <hip/hip_runtime.h>

// Problem constants (fixed by setup_inputs)
static constexpr int Bb = 2, Nn = 128, Ll = 128, Hh = 8, Ee = 64;
static constexpr float SCALE = 0.125f;  // 1/sqrt(E)

typedef short short8 __attribute__((ext_vector_type(8)));   // 8 bf16 in 4 VGPRs
typedef short short4v __attribute__((ext_vector_type(4)));  // 4 bf16 (8 B)
typedef float float4v __attribute__((ext_vector_type(4)));  // MFMA C/D

#define MFMA16(a, b, c) __builtin_amdgcn_mfma_f32_16x16x32_bf16(a, b, c, 0, 0, 0)

// ---- inline-asm staged loads: exact vmcnt counting, compiler can't move ---
__device__ inline float4 gload4(const float* p) {
  float4 r;
  asm volatile("global_load_dwordx4 %0, %1, off" : "=v"(r) : "v"(p) : "memory");
  return r;
}
__device__ inline float gload1(const float* p) {
  float r;
  asm volatile("global_load_dword %0, %1, off" : "=v"(r) : "v"(p) : "memory");
  return r;
}
#define WAIT_VM(N)                                        \
  do {                                                    \
    asm volatile("s_waitcnt vmcnt(" #N ")" ::: "memory"); \
    __builtin_amdgcn_sched_barrier(0);                    \
  } while (0)

__device__ inline unsigned short bf16_rne(float f) {
  unsigned u = __builtin_bit_cast(unsigned, f);
  u += 0x7FFFu + ((u >> 16) & 1u);
  return (unsigned short)(u >> 16);
}

// hi = bf16 truncation, lo = bf16 RNE of residual.  hi*hi + hi*lo + lo*hi
// reconstructs the product to ~2^-15.5 rel.
__device__ inline void split4(float4 a, short4v& hi, short4v& lo) {
  float f[4] = {a.x, a.y, a.z, a.w};
#pragma unroll
  for (int j = 0; j < 4; ++j) {
    unsigned u = __builtin_bit_cast(unsigned, f[j]);
    unsigned short h = (unsigned short)(u >> 16);
    hi[j] = (short)h;
    float hf = __builtin_bit_cast(float, (unsigned)h << 16);
    lo[j] = (short)bf16_rne(f[j] - hf);
  }
}

__device__ inline void split8(float4 a, float4 b, short8& hi, short8& lo) {
  float f[8] = {a.x, a.y, a.z, a.w, b.x, b.y, b.z, b.w};
#pragma unroll
  for (int j = 0; j < 8; ++j) {
    unsigned u = __builtin_bit_cast(unsigned, f[j]);
    unsigned short h = (unsigned short)(u >> 16);
    hi[j] = (short)h;
    float hf = __builtin_bit_cast(float, (unsigned)h << 16);
    lo[j] = (short)bf16_rne(f[j] - hf);
  }
}

__device__ inline short8 pack4(const unsigned* p) {
  union { unsigned u[4]; short8 s; } t;
  t.u[0] = p[0]; t.u[1] = p[1]; t.u[2] = p[2]; t.u[3] = p[3];
  return t.s;  // u32 = 2 consecutive bf16 (low halfword = even k) = frag pair
}

// LDS-only barrier: waits for this wave's DS ops (lgkmcnt) but leaves global
// loads (vmcnt) IN FLIGHT across the barrier.
__device__ inline void lds_barrier() {
  __builtin_amdgcn_sched_barrier(0);
  asm volatile("s_waitcnt lgkmcnt(0)" ::: "memory");
  __builtin_amdgcn_s_barrier();
  __builtin_amdgcn_sched_barrier(0);
}

// One block = one 128x128 attention group (b, idx, h), 8 waves x 16 rows.
//   P[r][c] = exp(SCALE * (mask?) * dot(Q[r],K[c]));  Out = (P*V) / rowsum(P)
//
// Round-10 = Round-8 structure (best verified) + XCD sibling swizzle:
//   the 8 h-blocks of one (b,idx) read adjacent 256-B slices of the SAME
//   2-KB Q/K/V rows; remapping blockIdx so those 8 siblings land on the
//   same XCD in the same dispatch window turns 8 sparse interleaved L2
//   streams into one dense per-XCD stream (L3/DRAM row locality).
//
// V_t intermediate: bf16, layout [B, L, H, M, E] (temporal writes 33.5 MB,
// spatial reads its slice as one contiguous 16 KB stream).
//
// SPATIAL=false (temporal): idx=n, rows=l, V=fp32 in [B,N,L,H,E], out=Vt bf16
// SPATIAL=true  (spatial) : idx=l, rows=n, V=Vt bf16, mask, out=fp32
template <bool SPATIAL>
__global__ __launch_bounds__(512, 3) void st_attn(
    const float* __restrict__ Qp, const float* __restrict__ Kp,
    const void* __restrict__ Vp, const float* __restrict__ Mp,
    void* __restrict__ Op, int idx_stride, int row_stride) {
  // Pb dual-purpose: phase A/B = K bf16 hi/lo planes (u16 [0,8192) hi,
  // [8192,16384) lo, fragment-linear + XOR swizzle); phase C/D = P bf16,
  // row-major stride 130.
  __shared__ __align__(16) unsigned short Pb[128 * 130];
  // V^T bf16: Vb[d][c], stride 130.  Total LDS 49,920 B -> 3 blocks/CU.
  __shared__ __align__(16) unsigned short Vb[64 * 130];

  // XCD sibling swizzle (bijective on [0,2048)): hw block i -> logical g
  // such that the 8 h-siblings of one (b,idx) occupy hw indices {c+8t},
  // all == c (mod 8) => same XCD, dispatched within 64 blocks of each other.
  const int i = blockIdx.x;
  const int g = (i >> 6) * 64 + (i & 7) * 8 + ((i >> 3) & 7);

  const int b = g >> 10;
  const int idx = (g >> 3) & 127;
  const int h = g & 7;
  const int base = b * (Nn * Ll * Hh * Ee) + idx * idx_stride + h * Ee;

  const int tid = threadIdx.x;
  const int wave = tid >> 6;   // 0..7
  const int lane = tid & 63;
  const int tx = lane & 15;    // MFMA m/n lane index
  const int quad = lane >> 4;  // MFMA k-chunk / row-quad
  const int rowbase = wave * 16;        // this wave's 16 output rows
  const int rowb = rowbase + quad * 4;  // C/D row = quad*4+e
  const int mb = b * (Nn * Nn);

  // ======== t0: issue ALL staged loads via asm (fixed order) ===============
  float4 kL[4], qL[4], vL[4];
  float mv[8][4];
#pragma unroll
  for (int it = 0; it < 4; ++it) {
    const int i4 = tid + it * 512;
    kL[it] = gload4(Kp + base + (i4 >> 4) * row_stride + ((i4 & 15) << 2));
  }
  {
    const float* qr = Qp + base + (rowbase + tx) * row_stride;
#pragma unroll
    for (int ks = 0; ks < 2; ++ks) {
      qL[ks * 2 + 0] = gload4(qr + ks * 32 + quad * 8);
      qL[ks * 2 + 1] = gload4(qr + ks * 32 + quad * 8 + 4);
    }
  }
  if constexpr (SPATIAL) {
    // V_t slice [b, idx=l, h, :, :] = 8192 bf16, contiguous.
    const unsigned short* Vt = (const unsigned short*)Vp;
    const unsigned short* vsl =
        Vt + ((b * Ll + idx) * Hh + h) * (Nn * Ee);
#pragma unroll
    for (int it = 0; it < 2; ++it) {
      const int i8 = tid + it * 512;  // 0..1023 chunks of 8 bf16
      vL[it] = gload4((const float*)(vsl + i8 * 8));
    }
    // Mask: 32 loads, issued LAST (youngest).
#pragma unroll
    for (int ct = 0; ct < 8; ++ct)
#pragma unroll
      for (int e = 0; e < 4; ++e)
        mv[ct][e] = gload1(Mp + mb + (rowb + e) * 128 + ct * 16 + tx);
    // outstanding: 4K + 4Q + 2V + 32M = 42
  } else {
    const float* Vf = (const float*)Vp;
#pragma unroll
    for (int it = 0; it < 4; ++it) {
      const int i4 = tid + it * 512;
      vL[it] = gload4(Vf + base + (i4 >> 4) * row_stride + ((i4 & 15) << 2));
    }
    // outstanding: 4K + 4Q + 4V = 12
  }

  // ======== phase A: K -> LDS planes (split), Q -> frags ===================
  if constexpr (SPATIAL) WAIT_VM(34);  // K+Q (oldest 8) landed
  else                   WAIT_VM(4);   // K+Q landed; V flying

  // Element K[r][d]: fragment F = ((r>>4)*8+(d>>3))*16+(r&15); F' = F^(d>>3).
  // u16 index = F'*8 + (d&7); lo plane at +8192 u16.
#pragma unroll
  for (int it = 0; it < 4; ++it) {
    const int i4 = tid + it * 512;
    const int r = i4 >> 4;             // K row 0..127
    const int d0 = (i4 & 15) << 2;     // K col 0..60
    const int vs = d0 >> 3;            // ks*4+quad of this chunk, 0..7
    const int idxk =
        ((((r >> 4) * 8 + vs) * 16 + (r & 15)) ^ vs) * 8 + (d0 & 7);
    short4v h4, l4;
    split4(kL[it], h4, l4);
    *(short4v*)(Pb + idxk) = h4;
    *(short4v*)(Pb + idxk + 8192) = l4;
  }

  short8 qhi[2], qlo[2];
#pragma unroll
  for (int ks = 0; ks < 2; ++ks)
    split8(qL[ks * 2 + 0], qL[ks * 2 + 1], qhi[ks], qlo[ks]);

  lds_barrier();  // A: K planes staged; V (+mask) loads still in flight

  // ======== phase B: score GEMM + softmax ==================================
  float4v acc[8];
#pragma unroll
  for (int ct = 0; ct < 8; ++ct) acc[ct] = (float4v)(0.0f);

  const short8* KS8 = (const short8*)Pb;
#pragma unroll
  for (int ct = 0; ct < 8; ++ct) {
#pragma unroll
    for (int ks = 0; ks < 2; ++ks) {
      const int vs = ks * 4 + quad;
      const int fi = (((ct * 8 + vs) * 16 + tx) ^ vs);
      const short8 khi = KS8[fi];
      const short8 klo = KS8[fi + 1024];  // lo plane: +1024 frags
      acc[ct] = MFMA16(qhi[ks], khi, acc[ct]);
      acc[ct] = MFMA16(qhi[ks], klo, acc[ct]);
      acc[ct] = MFMA16(qlo[ks], khi, acc[ct]);
    }
  }

  if constexpr (SPATIAL) WAIT_VM(0);  // mask + V landed (hidden under QK)

  float rowsum[4] = {0.f, 0.f, 0.f, 0.f};
#pragma unroll
  for (int ct = 0; ct < 8; ++ct) {
#pragma unroll
    for (int e = 0; e < 4; ++e) {
      float p = acc[ct][e] * SCALE;
      if (SPATIAL) p *= mv[ct][e];
      p = __expf(p);
      rowsum[e] += p;   // exact fp32 denominator (pre-rounding)
      acc[ct][e] = p;   // keep P in registers until Pb is free
    }
  }

  float inv[4];
#pragma unroll
  for (int e = 0; e < 4; ++e) {
    float s = rowsum[e];
#pragma unroll
    for (int d = 1; d < 16; d <<= 1) s += __shfl_xor(s, d);
    inv[e] = 1.0f / s;
  }

  lds_barrier();  // B: all waves done reading K planes -> Pb reusable

  // ======== phase C: P -> LDS, V -> LDS ====================================
#pragma unroll
  for (int ct = 0; ct < 8; ++ct) {
    const int col = ct * 16 + tx;
#pragma unroll
    for (int e = 0; e < 4; ++e)
      Pb[(rowb + e) * 130 + col] = bf16_rne(acc[ct][e]);
  }

  if constexpr (SPATIAL) {
    // V_t already bf16: unpack 8 bf16 per chunk into Vb[d][c=m].
#pragma unroll
    for (int it = 0; it < 2; ++it) {
      const int i8 = tid + it * 512;
      const int m = i8 >> 3;            // V_t row (node m) 0..127
      const int e0 = (i8 & 7) * 8;      // dim 0..56
      union { float4 f; unsigned short u[8]; } t;
      t.f = vL[it];
#pragma unroll
      for (int j = 0; j < 8; ++j) Vb[(e0 + j) * 130 + m] = t.u[j];
    }
  } else {
    WAIT_VM(0);  // V landed (latency hidden under phases A-B)
#pragma unroll
    for (int it = 0; it < 4; ++it) {
      const int i4 = tid + it * 512;
      const int c = i4 >> 4;             // V row 0..127
      const int d0 = (i4 & 15) << 2;     // V col 0..60
      const float4 v = vL[it];
      Vb[(d0 + 0) * 130 + c] = bf16_rne(v.x);
      Vb[(d0 + 1) * 130 + c] = bf16_rne(v.y);
      Vb[(d0 + 2) * 130 + c] = bf16_rne(v.z);
      Vb[(d0 + 3) * 130 + c] = bf16_rne(v.w);
    }
  }

  __syncthreads();  // C: P + V staged

  // ======== phase D: PV GEMM, normalize, store =============================
  float4v accO[4];
#pragma unroll
  for (int dt = 0; dt < 4; ++dt) accO[dt] = (float4v)(0.0f);

#pragma unroll
  for (int ks = 0; ks < 4; ++ks) {
    const unsigned* pw =
        (const unsigned*)Pb + (rowbase + tx) * 65 + ks * 16 + quad * 4;
    const short8 pA = pack4(pw);
#pragma unroll
    for (int dt = 0; dt < 4; ++dt) {
      const unsigned* vw =
          (const unsigned*)Vb + (dt * 16 + tx) * 65 + ks * 16 + quad * 4;
      const short8 vB = pack4(vw);
      accO[dt] = MFMA16(pA, vB, accO[dt]);
    }
  }

  if constexpr (SPATIAL) {
    float* O = (float*)Op;
#pragma unroll
    for (int dt = 0; dt < 4; ++dt)
#pragma unroll
      for (int e = 0; e < 4; ++e)
        O[base + (rowb + e) * row_stride + dt * 16 + tx] =
            accO[dt][e] * inv[e];
  } else {
    // V_t out: bf16, layout [B, L, H, M, E]; row = l, idx = n.
    unsigned short* O = (unsigned short*)Op;
#pragma unroll
    for (int dt = 0; dt < 4; ++dt)
#pragma unroll
      for (int e = 0; e < 4; ++e)
        O[((b * Ll + (rowb + e)) * Hh + h) * (Nn * Ee) + idx * Ee + dt * 16 +
          tx] = bf16_rne(accO[dt][e] * inv[e]);
  }
}

extern "C" void kernel_launch(void* const* d_in, const int* in_sizes, int n_in,
                              void* d_out, int out_size, void* d_ws,
                              size_t ws_size, hipStream_t stream) {
  const float* Q = (const float*)d_in[0];
  const float* K = (const float*)d_in[1];
  const float* V = (const float*)d_in[2];
  const float* M = (const float*)d_in[3];
  float* out = (float*)d_out;
  unsigned short* Vt = (unsigned short*)d_ws;  // 33.5 MiB bf16 [B,L,H,M,E]

  dim3 grid(Bb * Nn * Hh), blk(512);  // 2048 blocks x 8 waves
  // Temporal: per (b,n,h), rows = l
  st_attn<false><<<grid, blk, 0, stream>>>(Q, K, (const void*)V, nullptr,
                                           (void*)Vt, Ll * Hh * Ee /*n*/,
                                           Hh * Ee /*l*/);
  // Spatial: per (b,l,h), rows = n, V operand = V_t bf16
  st_attn<true><<<grid, blk, 0, stream>>>(Q, K, (const void*)Vt, M,
                                          (void*)out, Hh * Ee /*l*/,
                                          Ll * Hh * Ee /*n*/);
}